// Round 1
// 1339.536 us; speedup vs baseline: 1.8058x; 1.8058x over previous
//
#include <hip/hip_runtime.h>

// SparseGO: out[b][t] = sum_g x[b][g] * (weight[g][t] * mask[g][t])
// mask has <= 4 nonzeros (value 1.0) per gene row g.
//
// Fast path (needs ~333 MB workspace):
//   1) build_csc: wave-per-gene ballot scan of mask -> CSC buckets
//      csc[t][k] = {w, g} (term -> list of contributing genes), avg 16/term.
//   2) transpose_x: x[4096][20000] -> xT[20000][4096] (batch fast axis).
//   3) gather_out: out[b][t] = sum_k w_k * xT[g_k][b]; lanes = batch
//      (float4 per lane -> 1 KB coalesced wave loads), register accumulate,
//      coalesced out write via LDS tile. NO atomics in the hot loop.
// Fallback (small ws): previous verified scatter kernel.

#define BATCH  4096
#define GENES  20000
#define NTERMS 5000
#define MAXNZ  4
#define CAP    128   // CSC bucket capacity; counts are Poisson(16), max ~45
#define TTILE  32    // terms per gather block

// ---------------------------------------------------------------- fast path

__global__ __launch_bounds__(1024) void zero_counts(int* __restrict__ counts) {
  int i = blockIdx.x * 1024 + threadIdx.x;
  if (i < NTERMS) counts[i] = 0;
}

// one wave per gene: ballot-compact nonzero mask entries, scatter into CSC
__global__ __launch_bounds__(256) void build_csc(
    const float* __restrict__ mask, const float* __restrict__ weight,
    float2* __restrict__ csc, int* __restrict__ counts) {
  const int lane = threadIdx.x & 63;
  const int g = blockIdx.x * 4 + (threadIdx.x >> 6);
  const float* row = mask + (size_t)g * NTERMS;
  int base = 0;
  for (int it = 0; it < (NTERMS + 63) / 64; ++it) {
    const int t = it * 64 + lane;
    const float m = (t < NTERMS) ? row[t] : 0.0f;
    const unsigned long long bal = __ballot(m != 0.0f);
    if (m != 0.0f) {
      const int slot = base + __popcll(bal & ((1ull << lane) - 1ull));
      if (slot < MAXNZ) {  // mask has <= 4 nonzeros; guard is belt-and-braces
        const float w = weight[(size_t)g * NTERMS + t];
        const int pos = atomicAdd(&counts[t], 1);
        if (pos < CAP)
          csc[(size_t)t * CAP + pos] = make_float2(w, __int_as_float(g));
      }
    }
    base += __popcll(bal);
    if (base >= MAXNZ) break;  // uniform: early-out once all nnz found
  }
}

// 32x32 tiled transpose: x[b][g] -> xT[g][b]; 20000=625*32, 4096=128*32
__global__ __launch_bounds__(256) void transpose_x(
    const float* __restrict__ x, float* __restrict__ xT) {
  __shared__ float tile[32][33];
  const int g0 = blockIdx.x * 32;
  const int b0 = blockIdx.y * 32;
  const int lx = threadIdx.x;  // 0..31
  const int ly = threadIdx.y;  // 0..7
#pragma unroll
  for (int i = 0; i < 4; ++i)
    tile[ly + 8 * i][lx] = x[(size_t)(b0 + ly + 8 * i) * GENES + g0 + lx];
  __syncthreads();
#pragma unroll
  for (int i = 0; i < 4; ++i)
    xT[(size_t)(g0 + ly + 8 * i) * BATCH + b0 + lx] = tile[lx][ly + 8 * i];
}

// block: 256 threads = 4 waves; covers 256 batch rows x TTILE terms.
// Each wave handles 8 terms (2 at a time for MLP); lane carries 4 batch
// elements (float4) -> full wave spans all 256 batch rows per term.
__global__ __launch_bounds__(256) void gather_out(
    const float* __restrict__ xT, const float2* __restrict__ csc,
    const int* __restrict__ counts, float* __restrict__ out) {
  __shared__ float tile[TTILE * 260];  // [term][batch] + pad, 33.3 KB
  const int t0 = blockIdx.x * TTILE;
  const int nt = min(TTILE, NTERMS - t0);
  const int B0 = blockIdx.y * 256;
  const int w = threadIdx.x >> 6;
  const int lane = threadIdx.x & 63;
  const int boff = B0 + (lane << 2);

  for (int i = 0; i < 8; i += 2) {
    const int tl1 = w * 8 + i, tl2 = tl1 + 1;
    const bool v1 = tl1 < nt, v2 = tl2 < nt;
    const int t1 = t0 + tl1, t2 = t0 + tl2;
    const float2* l1 = csc + (size_t)(v1 ? t1 : 0) * CAP;
    const float2* l2 = csc + (size_t)(v2 ? t2 : 0) * CAP;
    const int n1 = v1 ? min(counts[t1], CAP) : 0;
    const int n2 = v2 ? min(counts[t2], CAP) : 0;
    float4 a1 = make_float4(0.f, 0.f, 0.f, 0.f);
    float4 a2 = make_float4(0.f, 0.f, 0.f, 0.f);
    const int nk = max(n1, n2);
    for (int k = 0; k < nk; ++k) {
      if (k < n1) {
        const float2 e = l1[k];  // wave-uniform broadcast
        const float4 xv =
            *(const float4*)(xT + (size_t)__float_as_int(e.y) * BATCH + boff);
        a1.x += e.x * xv.x; a1.y += e.x * xv.y;
        a1.z += e.x * xv.z; a1.w += e.x * xv.w;
      }
      if (k < n2) {
        const float2 e = l2[k];
        const float4 xv =
            *(const float4*)(xT + (size_t)__float_as_int(e.y) * BATCH + boff);
        a2.x += e.x * xv.x; a2.y += e.x * xv.y;
        a2.z += e.x * xv.z; a2.w += e.x * xv.w;
      }
    }
    if (v1) *(float4*)&tile[tl1 * 260 + (lane << 2)] = a1;
    if (v2) *(float4*)&tile[tl2 * 260 + (lane << 2)] = a2;
  }
  __syncthreads();

  // coalesced out write: lanes 0..31 -> terms, 2 batch rows per instruction
  const int tt = lane & 31;
  const int rh = lane >> 5;
  if (tt < nt) {
    for (int rb = w * 64; rb < w * 64 + 64; rb += 2) {
      const int r = rb + rh;
      out[(size_t)(B0 + r) * NTERMS + t0 + tt] = tile[tt * 260 + r];
    }
  }
}

// ---------------------------------------------------------------- fallback

#define RROWS  2

__global__ __launch_bounds__(256) void build_table(
    const float* __restrict__ mask, const float* __restrict__ weight,
    int* __restrict__ terms, float* __restrict__ wvals) {
  const int g = blockIdx.x;
  __shared__ int cnt;
  if (threadIdx.x == 0) cnt = 0;
  __syncthreads();

  const float4* row = (const float4*)(mask + (size_t)g * NTERMS);
  const int n4 = NTERMS / 4;
  for (int i = threadIdx.x; i < n4; i += 256) {
    float4 m = row[i];
    if (m.x != 0.f || m.y != 0.f || m.z != 0.f || m.w != 0.f) {
      const float mv[4] = {m.x, m.y, m.z, m.w};
#pragma unroll
      for (int j = 0; j < 4; ++j) {
        if (mv[j] != 0.f) {
          int slot = atomicAdd(&cnt, 1);
          if (slot < MAXNZ) {
            int t = i * 4 + j;
            terms[g * MAXNZ + slot] = t;
            wvals[g * MAXNZ + slot] = weight[(size_t)g * NTERMS + t];
          }
        }
      }
    }
  }
  __syncthreads();
  if (threadIdx.x == 0) {
    int c = cnt < MAXNZ ? cnt : MAXNZ;
    for (int s = c; s < MAXNZ; ++s) {
      terms[g * MAXNZ + s] = 0;
      wvals[g * MAXNZ + s] = 0.f;
    }
  }
}

__global__ __launch_bounds__(256) void spmm_scatter(
    const float* __restrict__ x,
    const int* __restrict__ terms, const float* __restrict__ wvals,
    float* __restrict__ out) {
  __shared__ float acc[RROWS * NTERMS];
  for (int i = threadIdx.x; i < RROWS * NTERMS; i += 256) acc[i] = 0.f;
  __syncthreads();

  const int b0 = blockIdx.x * RROWS;
  for (int g = threadIdx.x; g < GENES; g += 256) {
    const int4  t4 = ((const int4*)terms)[g];
    const float4 w4 = ((const float4*)wvals)[g];
#pragma unroll
    for (int r = 0; r < RROWS; ++r) {
      const float xv = x[(size_t)(b0 + r) * GENES + g];
      float* a = acc + r * NTERMS;
      atomicAdd(&a[t4.x], xv * w4.x);
      atomicAdd(&a[t4.y], xv * w4.y);
      atomicAdd(&a[t4.z], xv * w4.z);
      atomicAdd(&a[t4.w], xv * w4.w);
    }
  }
  __syncthreads();

#pragma unroll
  for (int r = 0; r < RROWS; ++r) {
    const float* a = acc + r * NTERMS;
    float* o = out + (size_t)(b0 + r) * NTERMS;
    for (int t = threadIdx.x; t < NTERMS; t += 256) o[t] = a[t];
  }
}

// ---------------------------------------------------------------- launch

extern "C" void kernel_launch(void* const* d_in, const int* in_sizes, int n_in,
                              void* d_out, int out_size, void* d_ws, size_t ws_size,
                              hipStream_t stream) {
  const float* x      = (const float*)d_in[0];
  const float* weight = (const float*)d_in[1];
  const float* mask   = (const float*)d_in[2];
  float* out = (float*)d_out;

  const size_t xT_bytes     = (size_t)GENES * BATCH * 4;        // 327,680,000
  const size_t csc_bytes    = (size_t)NTERMS * CAP * 8 + 16;    //   5,120,016
  const size_t counts_bytes = (size_t)NTERMS * 4;               //      20,000
  const size_t need = xT_bytes + csc_bytes + counts_bytes;      // ~333 MB

  if (ws_size >= need) {
    float*  xT     = (float*)d_ws;
    float2* csc    = (float2*)((char*)d_ws + xT_bytes);
    int*    counts = (int*)((char*)d_ws + xT_bytes + csc_bytes);

    zero_counts<<<(NTERMS + 1023) / 1024, 1024, 0, stream>>>(counts);
    build_csc<<<GENES / 4, 256, 0, stream>>>(mask, weight, csc, counts);
    transpose_x<<<dim3(GENES / 32, BATCH / 32), dim3(32, 8), 0, stream>>>(x, xT);
    gather_out<<<dim3((NTERMS + TTILE - 1) / TTILE, BATCH / 256), 256, 0, stream>>>(
        xT, csc, counts, out);
  } else {
    int*   terms = (int*)d_ws;
    float* wvals = (float*)((char*)d_ws + (size_t)GENES * MAXNZ * 4);

    build_table<<<GENES, 256, 0, stream>>>(mask, weight, terms, wvals);
    spmm_scatter<<<BATCH / RROWS, 256, 0, stream>>>(x, terms, wvals, out);
  }
}

// Round 2
// 1249.150 us; speedup vs baseline: 1.9364x; 1.0724x over previous
//
#include <hip/hip_runtime.h>

// SparseGO: out[b][t] = sum_g x[b][g] * (weight[g][t] * mask[g][t])
// mask has 1..4 nonzeros (value 1.0) per gene row g (random term ids, dups
// possible). nnz_total <= 80000.
//
// Pipeline (needs only ~2.6 MB workspace):
//   1) zero_counts
//   2) build_csc: wave-per-gene float4 scan of mask (early-out after 4 nz)
//      -> k-slab transposed CSC: cscT[k*NTERMS + t] = {w, g}. Slab layout
//      makes the consumer's metadata reads coalesced across term-lanes.
//   3) row_spmm: one block per batch row. Stage x[b][0..20000) (80 KB) in
//      LDS once (coalesced float4, read from HBM exactly once); lanes = terms;
//      out[b][t] = sum_k w_k * xrow[g_k] with LDS gathers. No transpose, no
//      atomics, no xT overfetch.
// Fallback (tiny ws): previous verified scatter kernel.

#define BATCH  4096
#define GENES  20000
#define NTERMS 5000
#define MAXNZ  4
#define CAP    64     // per-term bucket cap; counts ~Poisson(16), P(>=64)~1e-19
#define RTHREADS 1024

// ---------------------------------------------------------------- fast path

__global__ __launch_bounds__(1024) void zero_counts(int* __restrict__ counts) {
  int i = blockIdx.x * 1024 + threadIdx.x;
  if (i < NTERMS) counts[i] = 0;
}

// one wave per gene: float4 scan, per-component ballot count, early-out.
__global__ __launch_bounds__(256) void build_csc(
    const float* __restrict__ mask, const float* __restrict__ weight,
    float2* __restrict__ cscT, int* __restrict__ counts) {
  const int lane = threadIdx.x & 63;
  const int g = blockIdx.x * 4 + (threadIdx.x >> 6);
  const float4* row4 = (const float4*)(mask + (size_t)g * NTERMS);
  const int n4 = NTERMS / 4;  // 1250
  int found = 0;
  for (int it = 0; it < (n4 + 63) / 64 && found < MAXNZ; ++it) {
    const int i = it * 64 + lane;
    float4 m = make_float4(0.f, 0.f, 0.f, 0.f);
    if (i < n4) m = row4[i];
    const float mv[4] = {m.x, m.y, m.z, m.w};
    const bool nz = (m.x != 0.f) | (m.y != 0.f) | (m.z != 0.f) | (m.w != 0.f);
    if (nz) {
#pragma unroll
      for (int j = 0; j < 4; ++j) {
        if (mv[j] != 0.f) {
          const int t = i * 4 + j;
          const float w = weight[(size_t)g * NTERMS + t];
          const int pos = atomicAdd(&counts[t], 1);
          if (pos < CAP)
            cscT[(size_t)pos * NTERMS + t] = make_float2(w, __int_as_float(g));
        }
      }
    }
    found += __popcll(__ballot(m.x != 0.f)) + __popcll(__ballot(m.y != 0.f)) +
             __popcll(__ballot(m.z != 0.f)) + __popcll(__ballot(m.w != 0.f));
  }
}

// one block per batch row: x row staged in LDS, lanes over terms.
__global__ __launch_bounds__(1024) void row_spmm(
    const float* __restrict__ x, const float2* __restrict__ cscT,
    const int* __restrict__ counts, float* __restrict__ out) {
  __shared__ __align__(16) float xrow[GENES];  // 80,000 B -> 2 blocks/CU
  const int b = blockIdx.x;
  {
    const float4* xr4 = (const float4*)(x + (size_t)b * GENES);
    float4* s4 = (float4*)xrow;
    for (int i = threadIdx.x; i < GENES / 4; i += RTHREADS) s4[i] = xr4[i];
  }
  __syncthreads();

  float* orow = out + (size_t)b * NTERMS;
  for (int t0 = 0; t0 < NTERMS; t0 += 2 * RTHREADS) {
    const int t1 = t0 + threadIdx.x;
    const int t2 = t1 + RTHREADS;
    const bool v1 = t1 < NTERMS, v2 = t2 < NTERMS;
    const int n1 = v1 ? min(counts[t1], CAP) : 0;
    const int n2 = v2 ? min(counts[t2], CAP) : 0;
    float a1 = 0.f, a2 = 0.f;
    const float2* p1 = cscT + t1;
    const float2* p2 = cscT + t2;
    const int nk = max(n1, n2);
    for (int k = 0; k < nk; ++k) {
      if (k < n1) {
        const float2 e = p1[(size_t)k * NTERMS];  // coalesced across lanes
        a1 += e.x * xrow[__float_as_int(e.y)];    // LDS gather
      }
      if (k < n2) {
        const float2 e = p2[(size_t)k * NTERMS];
        a2 += e.x * xrow[__float_as_int(e.y)];
      }
    }
    if (v1) orow[t1] = a1;
    if (v2) orow[t2] = a2;
  }
}

// ---------------------------------------------------------------- fallback

#define RROWS  2

__global__ __launch_bounds__(256) void build_table(
    const float* __restrict__ mask, const float* __restrict__ weight,
    int* __restrict__ terms, float* __restrict__ wvals) {
  const int g = blockIdx.x;
  __shared__ int cnt;
  if (threadIdx.x == 0) cnt = 0;
  __syncthreads();

  const float4* row = (const float4*)(mask + (size_t)g * NTERMS);
  const int n4 = NTERMS / 4;
  for (int i = threadIdx.x; i < n4; i += 256) {
    float4 m = row[i];
    if (m.x != 0.f || m.y != 0.f || m.z != 0.f || m.w != 0.f) {
      const float mv[4] = {m.x, m.y, m.z, m.w};
#pragma unroll
      for (int j = 0; j < 4; ++j) {
        if (mv[j] != 0.f) {
          int slot = atomicAdd(&cnt, 1);
          if (slot < MAXNZ) {
            int t = i * 4 + j;
            terms[g * MAXNZ + slot] = t;
            wvals[g * MAXNZ + slot] = weight[(size_t)g * NTERMS + t];
          }
        }
      }
    }
  }
  __syncthreads();
  if (threadIdx.x == 0) {
    int c = cnt < MAXNZ ? cnt : MAXNZ;
    for (int s = c; s < MAXNZ; ++s) {
      terms[g * MAXNZ + s] = 0;
      wvals[g * MAXNZ + s] = 0.f;
    }
  }
}

__global__ __launch_bounds__(256) void spmm_scatter(
    const float* __restrict__ x,
    const int* __restrict__ terms, const float* __restrict__ wvals,
    float* __restrict__ out) {
  __shared__ float acc[RROWS * NTERMS];
  for (int i = threadIdx.x; i < RROWS * NTERMS; i += 256) acc[i] = 0.f;
  __syncthreads();

  const int b0 = blockIdx.x * RROWS;
  for (int g = threadIdx.x; g < GENES; g += 256) {
    const int4  t4 = ((const int4*)terms)[g];
    const float4 w4 = ((const float4*)wvals)[g];
#pragma unroll
    for (int r = 0; r < RROWS; ++r) {
      const float xv = x[(size_t)(b0 + r) * GENES + g];
      float* a = acc + r * NTERMS;
      atomicAdd(&a[t4.x], xv * w4.x);
      atomicAdd(&a[t4.y], xv * w4.y);
      atomicAdd(&a[t4.z], xv * w4.z);
      atomicAdd(&a[t4.w], xv * w4.w);
    }
  }
  __syncthreads();

#pragma unroll
  for (int r = 0; r < RROWS; ++r) {
    const float* a = acc + r * NTERMS;
    float* o = out + (size_t)(b0 + r) * NTERMS;
    for (int t = threadIdx.x; t < NTERMS; t += 256) o[t] = a[t];
  }
}

// ---------------------------------------------------------------- launch

extern "C" void kernel_launch(void* const* d_in, const int* in_sizes, int n_in,
                              void* d_out, int out_size, void* d_ws, size_t ws_size,
                              hipStream_t stream) {
  const float* x      = (const float*)d_in[0];
  const float* weight = (const float*)d_in[1];
  const float* mask   = (const float*)d_in[2];
  float* out = (float*)d_out;

  const size_t csc_bytes    = (size_t)CAP * NTERMS * 8;   // 2,560,000
  const size_t counts_bytes = (size_t)NTERMS * 4;         //    20,000
  const size_t need = csc_bytes + counts_bytes;           // ~2.6 MB

  if (ws_size >= need) {
    float2* cscT   = (float2*)d_ws;
    int*    counts = (int*)((char*)d_ws + csc_bytes);

    zero_counts<<<(NTERMS + 1023) / 1024, 1024, 0, stream>>>(counts);
    build_csc<<<GENES / 4, 256, 0, stream>>>(mask, weight, cscT, counts);
    row_spmm<<<BATCH, RTHREADS, 0, stream>>>(x, cscT, counts, out);
  } else {
    int*   terms = (int*)d_ws;
    float* wvals = (float*)((char*)d_ws + (size_t)GENES * MAXNZ * 4);

    build_table<<<GENES, 256, 0, stream>>>(mask, weight, terms, wvals);
    spmm_scatter<<<BATCH / RROWS, 256, 0, stream>>>(x, terms, wvals, out);
  }
}

// Round 3
// 1072.365 us; speedup vs baseline: 2.2557x; 1.1649x over previous
//
#include <hip/hip_runtime.h>

// SparseGO: out[b][t] = sum_g x[b][g] * (weight[g][t] * mask[g][t])
// mask has 1..4 nonzeros (value 1.0) per gene row g. nnz_total <= 80000.
//
// Pipeline (~2.6 MB workspace):
//   1) zero_ws: clear cscP + counts (padding entries must read {w=0,g=0}).
//   2) build_csc: persistent grid-stride streaming scan of mask (2048 blocks,
//      ~48 independent float4 loads/thread -> HBM-saturating; the old
//      wave-per-gene version ran at 0.5 TB/s because 5-iteration short-lived
//      blocks never built up enough in-flight reads). Nonzeros (rare) go via
//      global atomics into a PAIR-PACKED transposed CSC:
//      cscP[p][t] = float4{w0,g0,w1,g1} for entries k=2p,2p+1 of term t.
//   3) row_spmm: one block per batch row; x row (80 KB) staged in LDS once;
//      lanes = terms; one coalesced dwordx4 metadata load = 2 entries, with
//      explicit next-pair prefetch to break the load->gather serial chain.
// Fallback (tiny ws): previous verified scatter kernel.

#define BATCH  4096
#define GENES  20000
#define NTERMS 5000
#define MAXNZ  4
#define CAP    64     // per-term cap; counts ~Poisson(16), P(>=64) ~ 1e-19
#define RTHREADS 1024
#define SBLK   2048   // persistent blocks for the streaming scan

// ---------------------------------------------------------------- fast path

// clear cscP (2.56 MB) + counts (20 KB) in one pass
__global__ __launch_bounds__(256) void zero_ws(float4* __restrict__ ws,
                                               int n16) {
  const int stride = gridDim.x * 256;
  for (int i = blockIdx.x * 256 + threadIdx.x; i < n16; i += stride)
    ws[i] = make_float4(0.f, 0.f, 0.f, 0.f);
}

// persistent streaming nz-scan of mask -> pair-packed CSC
__global__ __launch_bounds__(256) void build_csc(
    const float* __restrict__ mask, const float* __restrict__ weight,
    float2* __restrict__ cscP, int* __restrict__ counts) {
  const int n4 = GENES * NTERMS / 4;  // 25,000,000 float4s
  const float4* m4 = (const float4*)mask;
  const int stride = SBLK * 256;
  for (int i = blockIdx.x * 256 + threadIdx.x; i < n4; i += stride) {
    const float4 m = m4[i];
    if (m.x != 0.f || m.y != 0.f || m.z != 0.f || m.w != 0.f) {
      const float mv[4] = {m.x, m.y, m.z, m.w};
#pragma unroll
      for (int j = 0; j < 4; ++j) {
        if (mv[j] != 0.f) {
          const int e = i * 4 + j;          // < 1e8, fits int
          const int g = e / NTERMS;         // magic-mul const division
          const int t = e - g * NTERMS;
          const float w = weight[e];
          const int pos = atomicAdd(&counts[t], 1);
          if (pos < CAP)
            cscP[(size_t)(pos >> 1) * (2 * NTERMS) + 2 * t + (pos & 1)] =
                make_float2(w, __int_as_float(g));
        }
      }
    }
  }
}

// one block per batch row: x row in LDS, lanes over terms, pair-packed
// metadata with explicit prefetch.
__global__ __launch_bounds__(1024) void row_spmm(
    const float* __restrict__ x, const float4* __restrict__ cscP,
    const int* __restrict__ counts, float* __restrict__ out) {
  __shared__ __align__(16) float xrow[GENES];  // 80 KB -> 2 blocks/CU
  const int b = blockIdx.x;
  {
    const float4* xr4 = (const float4*)(x + (size_t)b * GENES);
    float4* s4 = (float4*)xrow;
    for (int i = threadIdx.x; i < GENES / 4; i += RTHREADS) s4[i] = xr4[i];
  }
  __syncthreads();

  const float4 z4 = make_float4(0.f, 0.f, 0.f, 0.f);
  float* orow = out + (size_t)b * NTERMS;
  for (int t0 = 0; t0 < NTERMS; t0 += 2 * RTHREADS) {
    const int t1 = t0 + threadIdx.x;
    const int t2 = t1 + RTHREADS;
    const bool v1 = t1 < NTERMS, v2 = t2 < NTERMS;
    const int np1 = v1 ? (min(counts[t1], CAP) + 1) >> 1 : 0;
    const int np2 = v2 ? (min(counts[t2], CAP) + 1) >> 1 : 0;
    const float4* q1 = cscP + (v1 ? t1 : 0);
    const float4* q2 = cscP + (v2 ? t2 : 0);
    float a1 = 0.f, a2 = 0.f;
    const int npm = max(np1, np2);
    float4 f1 = (np1 > 0) ? q1[0] : z4;   // prefetch pair 0
    float4 f2 = (np2 > 0) ? q2[0] : z4;
    for (int p = 0; p < npm; ++p) {
      const float4 c1 = f1, c2 = f2;
      if (p + 1 < np1) f1 = q1[(size_t)(p + 1) * NTERMS];  // prefetch next
      if (p + 1 < np2) f2 = q2[(size_t)(p + 1) * NTERMS];
      if (p < np1) {
        a1 += c1.x * xrow[__float_as_int(c1.y)];
        a1 += c1.z * xrow[__float_as_int(c1.w)];
      }
      if (p < np2) {
        a2 += c2.x * xrow[__float_as_int(c2.y)];
        a2 += c2.z * xrow[__float_as_int(c2.w)];
      }
    }
    if (v1) orow[t1] = a1;
    if (v2) orow[t2] = a2;
  }
}

// ---------------------------------------------------------------- fallback

#define RROWS  2

__global__ __launch_bounds__(256) void build_table(
    const float* __restrict__ mask, const float* __restrict__ weight,
    int* __restrict__ terms, float* __restrict__ wvals) {
  const int g = blockIdx.x;
  __shared__ int cnt;
  if (threadIdx.x == 0) cnt = 0;
  __syncthreads();

  const float4* row = (const float4*)(mask + (size_t)g * NTERMS);
  const int n4 = NTERMS / 4;
  for (int i = threadIdx.x; i < n4; i += 256) {
    float4 m = row[i];
    if (m.x != 0.f || m.y != 0.f || m.z != 0.f || m.w != 0.f) {
      const float mv[4] = {m.x, m.y, m.z, m.w};
#pragma unroll
      for (int j = 0; j < 4; ++j) {
        if (mv[j] != 0.f) {
          int slot = atomicAdd(&cnt, 1);
          if (slot < MAXNZ) {
            int t = i * 4 + j;
            terms[g * MAXNZ + slot] = t;
            wvals[g * MAXNZ + slot] = weight[(size_t)g * NTERMS + t];
          }
        }
      }
    }
  }
  __syncthreads();
  if (threadIdx.x == 0) {
    int c = cnt < MAXNZ ? cnt : MAXNZ;
    for (int s = c; s < MAXNZ; ++s) {
      terms[g * MAXNZ + s] = 0;
      wvals[g * MAXNZ + s] = 0.f;
    }
  }
}

__global__ __launch_bounds__(256) void spmm_scatter(
    const float* __restrict__ x,
    const int* __restrict__ terms, const float* __restrict__ wvals,
    float* __restrict__ out) {
  __shared__ float acc[RROWS * NTERMS];
  for (int i = threadIdx.x; i < RROWS * NTERMS; i += 256) acc[i] = 0.f;
  __syncthreads();

  const int b0 = blockIdx.x * RROWS;
  for (int g = threadIdx.x; g < GENES; g += 256) {
    const int4  t4 = ((const int4*)terms)[g];
    const float4 w4 = ((const float4*)wvals)[g];
#pragma unroll
    for (int r = 0; r < RROWS; ++r) {
      const float xv = x[(size_t)(b0 + r) * GENES + g];
      float* a = acc + r * NTERMS;
      atomicAdd(&a[t4.x], xv * w4.x);
      atomicAdd(&a[t4.y], xv * w4.y);
      atomicAdd(&a[t4.z], xv * w4.z);
      atomicAdd(&a[t4.w], xv * w4.w);
    }
  }
  __syncthreads();

#pragma unroll
  for (int r = 0; r < RROWS; ++r) {
    const float* a = acc + r * NTERMS;
    float* o = out + (size_t)(b0 + r) * NTERMS;
    for (int t = threadIdx.x; t < NTERMS; t += 256) o[t] = a[t];
  }
}

// ---------------------------------------------------------------- launch

extern "C" void kernel_launch(void* const* d_in, const int* in_sizes, int n_in,
                              void* d_out, int out_size, void* d_ws, size_t ws_size,
                              hipStream_t stream) {
  const float* x      = (const float*)d_in[0];
  const float* weight = (const float*)d_in[1];
  const float* mask   = (const float*)d_in[2];
  float* out = (float*)d_out;

  const size_t csc_bytes    = (size_t)CAP * NTERMS * 8;   // 2,560,000 (16B-mult)
  const size_t counts_bytes = (size_t)NTERMS * 4;         //    20,000
  const size_t need = csc_bytes + counts_bytes;           // ~2.6 MB

  if (ws_size >= need) {
    float2* cscP   = (float2*)d_ws;
    int*    counts = (int*)((char*)d_ws + csc_bytes);
    const int n16 = (int)((csc_bytes + counts_bytes + 15) / 16);

    zero_ws<<<640, 256, 0, stream>>>((float4*)d_ws, n16);
    build_csc<<<SBLK, 256, 0, stream>>>(mask, weight, cscP, counts);
    row_spmm<<<BATCH, RTHREADS, 0, stream>>>(x, (const float4*)cscP, counts, out);
  } else {
    int*   terms = (int*)d_ws;
    float* wvals = (float*)((char*)d_ws + (size_t)GENES * MAXNZ * 4);

    build_table<<<GENES, 256, 0, stream>>>(mask, weight, terms, wvals);
    spmm_scatter<<<BATCH / RROWS, 256, 0, stream>>>(x, terms, wvals, out);
  }
}